// Round 12
// baseline (212.521 us; speedup 1.0000x reference)
//
#include <hip/hip_runtime.h>
#include <hip/hip_bf16.h>

using f16 = _Float16;
typedef _Float16 f16x8 __attribute__((ext_vector_type(8)));
typedef _Float16 f16x4 __attribute__((ext_vector_type(4)));
typedef float f32x4 __attribute__((ext_vector_type(4)));

#define AS1 __attribute__((address_space(1)))
#define AS3 __attribute__((address_space(3)))

// Problem constants
constexpr int Bc = 4, Qc = 1024, Dc = 1024, Nh = 16, DHc = 64;
constexpr int BQ = Bc * Qc;      // 4096 rows of w
constexpr int NHEAD = Bc * Nh;   // 64 (b,n) heads
constexpr float ATT_SCALE = 0.125f;
constexpr float LOG2E = 1.44269504088896f;

// ---------------- merged preprocessing: f2h | 4-way transpose | rel-shift r_emb ----------------
struct Ptr4 { const float* p[4]; };
__global__ __launch_bounds__(256) void k_prep(
    const float* __restrict__ w_in, f16* __restrict__ wh,
    Ptr4 srcs, f16* __restrict__ WT,
    const float* __restrict__ remb, f16* __restrict__ Ke)
{
    const int bid = blockIdx.x, tid = threadIdx.x;
    if (bid < 2048) {
        long i8 = ((long)bid * 256 + tid) * 8;
        float4 a = *(const float4*)&w_in[i8];
        float4 b = *(const float4*)&w_in[i8 + 4];
        f16x8 o = { (f16)a.x, (f16)a.y, (f16)a.z, (f16)a.w,
                    (f16)b.x, (f16)b.y, (f16)b.z, (f16)b.w };
        *(f16x8*)&wh[i8] = o;
    } else if (bid < 6144) {
        __shared__ f16 tile[32][33];
        int idx = bid - 2048;
        int z = idx >> 10, rem = idx & 1023;
        int r0 = (rem >> 5) * 32, c0 = (rem & 31) * 32;
        const float* src = srcs.p[z];
        f16* d = WT + (long)z * Dc * Dc;
        int tx = tid & 31, ty = tid >> 5;   // 32 x 8
#pragma unroll
        for (int dy = 0; dy < 32; dy += 8) {
            int r = r0 + ty + dy, c = c0 + tx;
            tile[ty + dy][tx] = (f16)src[(long)r * Dc + c];
        }
        __syncthreads();
#pragma unroll
        for (int dy = 0; dy < 32; dy += 8) {
            int c = c0 + ty + dy, r = r0 + tx;
            d[(long)c * Dc + r] = tile[tx][ty + dy];
        }
    } else {
        long gid = (long)(bid - 6144) * 256 + tid;  // 64*1024*8
        int d8 = (int)(gid & 7) * 8;
        int j = (int)((gid >> 3) & 1023);
        int h = (int)(gid >> 13);
        int n = h & 15;
        f16x8 kv;
        if (j < 1023) {
            const float* rp = &remb[((long)(j + 1) * 16 + n) * 64 + d8];
            float4 r0 = *(const float4*)rp, r1 = *(const float4*)(rp + 4);
            kv[0] = (f16)r0.x; kv[1] = (f16)r0.y; kv[2] = (f16)r0.z; kv[3] = (f16)r0.w;
            kv[4] = (f16)r1.x; kv[5] = (f16)r1.y; kv[6] = (f16)r1.z; kv[7] = (f16)r1.w;
        } else {
            kv = f16x8{};
        }
        *(f16x8*)&Ke[(((long)h << 10) + j) * 64 + d8] = kv;
    }
}

// ---------------- NT GEMM v3: BK=32 async dbuf + FINE TILES for TLP ----------------
// R11 diagnosis: dbuf killed staging VALU (33.6->15.6) and conflicts=0, but
// all pipes <35% busy at 3 blocks/CU -> latency-bound on TLP. R9 proved the
// occupancy direction; apply it: QKV 64x128 tile -> 1536 blocks = 6/CU =
// 24 waves/CU (LDS 24KB x 6 = 144 <= 160; launch_bounds(256,6) caps VGPR 85).
// Wo 64x64 -> 1024 blocks = 4/CU. Extra L2 staging traffic (~+192MB @34.5TB/s
// ~ +6us) is the price; stall reclaim should dominate.
// K-accumulation order per output element unchanged -> bit-identical output.
// Tripwires: conflicts < 0.5M, absmax == 0.03125, LDS_Block_Size 24576 (QKV).
template <int BM, int BN, int BK, int WROWS, int WCOLS, int EPI>
__global__ __launch_bounds__(256, 6) void k_gemm_nt(
    const f16* __restrict__ A, const f16* __restrict__ Bt, void* __restrict__ Cv,
    f16* __restrict__ qtp, f16* __restrict__ ktp, f16* __restrict__ vtp,
    int lda, int ldb, int ldc, int K)
{
    static_assert(BK == 32, "geometry below assumes BK=32 double-buffered");
    constexpr int TM = BM / (WROWS * 16);
    constexpr int TN = BN / (WCOLS * 16);
    __shared__ __align__(16) f16 sA[2][BM * 32];
    __shared__ __align__(16) f16 sB[2][BN * 32];

    const int tid = threadIdx.x;
    const int lane = tid & 63, wave = tid >> 6;
    const int wm = wave / WCOLS, wn = wave % WCOLS;

    const int nwg = gridDim.x * gridDim.y;
    const int flat = blockIdx.y * gridDim.x + blockIdx.x;
    const int cpx = nwg >> 3;
    const int swz = (flat & 7) * cpx + (flat >> 3);
    const int bx = swz % gridDim.x, by = swz / gridDim.x;
    const int m0 = by * BM, n0 = bx * BN;

    f32x4 acc[TM][TN] = {};

    const int lrow = lane & 15;
    const int quad = lane >> 4;
    // staging: 1KB chunk = 16 rows x 32 f16 (64B rows); 4 lanes/row
    const int srow = lane >> 2;                             // row within chunk
    const int scol = ((lane & 3) ^ ((srow >> 1) & 3)) * 8;  // inv-swizzled src chunk
    const int rsw2 = (lrow >> 1) & 3;                       // read-side swizzle

    auto stage = [&](int buf, int k0) {
        constexpr int CHA = BM / 16;   // 1KB chunks per A tile
#pragma unroll
        for (int ch = 0; ch < (CHA + 3) / 4; ++ch) {
            int cc = ch * 4 + wave;
            if (cc < CHA)
                __builtin_amdgcn_global_load_lds(
                    (const AS1 void*)(const void*)&A[(long)(m0 + cc * 16 + srow) * lda + k0 + scol],
                    (AS3 void*)(void*)&sA[buf][cc * 512], 16, 0, 0);
        }
        constexpr int CHB = BN / 16;
#pragma unroll
        for (int ch = 0; ch < (CHB + 3) / 4; ++ch) {
            int cc = ch * 4 + wave;
            if (cc < CHB)
                __builtin_amdgcn_global_load_lds(
                    (const AS1 void*)(const void*)&Bt[(long)(n0 + cc * 16 + srow) * ldb + k0 + scol],
                    (AS3 void*)(void*)&sB[buf][cc * 512], 16, 0, 0);
        }
    };

    // prologue: stage tile 0
    stage(0, 0);
    __syncthreads();

    const int NKT = K / 32;
    for (int kt = 0; kt < NKT; ++kt) {
        const int cur = kt & 1;
        // issue next tile's async loads FIRST (in flight across compute below)
        if (kt + 1 < NKT) stage(cur ^ 1, (kt + 1) * 32);

        f16x8 af[TM], bfr[TN];
#pragma unroll
        for (int mi = 0; mi < TM; ++mi) {
            int R = wm * TM * 16 + mi * 16 + lrow;
            af[mi] = *(const f16x8*)&sA[cur][R * 32 + (quad ^ rsw2) * 8];
        }
#pragma unroll
        for (int ni = 0; ni < TN; ++ni) {
            int R = wn * TN * 16 + ni * 16 + lrow;
            bfr[ni] = *(const f16x8*)&sB[cur][R * 32 + (quad ^ rsw2) * 8];
        }
#pragma unroll
        for (int mi = 0; mi < TM; ++mi)
#pragma unroll
            for (int ni = 0; ni < TN; ++ni)
                acc[mi][ni] = __builtin_amdgcn_mfma_f32_16x16x32_f16(af[mi], bfr[ni], acc[mi][ni], 0, 0, 0);

        if (kt + 1 < NKT)
            __syncthreads();   // drains vmcnt (next tile resident) + reads of cur done
    }

    const int crow = (lane >> 4) * 4;
    const int ccol = lane & 15;
#pragma unroll
    for (int mi = 0; mi < TM; ++mi)
#pragma unroll
        for (int ni = 0; ni < TN; ++ni)
#pragma unroll
            for (int r = 0; r < 4; ++r) {
                int gm = m0 + wm * TM * 16 + mi * 16 + crow + r;
                int gn = n0 + wn * TN * 16 + ni * 16 + ccol;
                float val = acc[mi][ni][r];
                if constexpr (EPI == 0) {
                    ((f16*)Cv)[(long)gm * ldc + gn] = (f16)val;
                } else {
                    int seg = n0 >> 10;       // block-uniform (BN divides 1024)
                    int col = gn & 1023;
                    if (seg == 0) {
                        qtp[(long)gm * 1024 + col] = (f16)val;
                    } else if (seg == 1) {
                        ktp[(long)gm * 1024 + col] = (f16)val;
                    } else {
                        int b = gm >> 10, i = gm & 1023;
                        vtp[(((long)(b << 10) + col) << 10) + i] = (f16)val;
                    }
                }
            }
}

// ---------------- fused flash attention v13 (R8 config, setprio REVERTED).
// R11 A/B: setprio +2.1us regression (R8 47.1 vs R11 49.2, identical counters).
// Mechanism: 8 waves barrier-locked (m190 lockstep regime) and the prio-0
// region contained the softmax critical chain -> it lost arbitration to the
// other block's prio-1 MFMA. Keep v13 exactly as measured at 47.1us.
// Tripwires: WRITE_SIZE == 8192 KB, VGPR <= 64, FETCH ~16.7MB, conflicts
// == 4194304, absmax == 0.03125.
__global__ __launch_bounds__(512, 4) void k_flash(
    const f16* __restrict__ qh, const f16* __restrict__ kh,
    const f16* __restrict__ Ke, const f16* __restrict__ vT,
    const float* __restrict__ rwb, const float* __restrict__ r_bias,
    f16* __restrict__ avp)
{
    __shared__ __align__(16) f16 sKa[2][64 * 64];   // kh tile: [j-local][d]
    __shared__ __align__(16) f16 sKe[2][64 * 64];   // Ke tile: [j-local][d]
    __shared__ __align__(16) f16 sVa[2][64 * 64];   // vT tile: [d][j-local]
    __shared__ float sRB[2][64];

    const int tid = threadIdx.x, lane = tid & 63, wave = tid >> 6;  // wave 0..7
    const int bid = blockIdx.x;
    const int h = (((bid >> 3) & 7) << 3) | (bid & 7);
    const int i0 = (bid >> 6) * 128;
    const int b = h >> 4, n = h & 15;

    const int lrow = lane & 15;            // q (B-frag n) / row index
    const int quad = lane >> 4;
    const int lr3 = lane >> 3;             // staging: row within wave's 8-row slice
    const int swc = (lane & 7) ^ (lr3 & 7);  // inverse-swizzled source 16B chunk

    // wave-slice per-lane source pointers (tile row = 8*wave + lr3)
    const f16* srcK = kh + ((long)(b * Qc) + 8 * wave + lr3) * 1024 + n * 64 + swc * 8;
    const f16* srcE = Ke + ((long)h * Qc + 8 * wave + lr3) * 64 + swc * 8;
    const f16* srcV = vT + (long)h * DHc * Qc + (long)(8 * wave + lr3) * Qc + swc * 8;

    // r_w_bias fragments (f32 -> f16), pre-scaled by ATT_SCALE
    f16x8 rw0, rw1;
#pragma unroll
    for (int e = 0; e < 8; ++e) {
        rw0[e] = (f16)(rwb[n * 64 + quad * 8 + e] * ATT_SCALE);
        rw1[e] = (f16)(rwb[n * 64 + 32 + quad * 8 + e] * ATT_SCALE);
    }

    // Q fragments (B-operand of S^T): wave owns q rows [i0+wave*16, +16).
    const f16 qsc = (f16)0.125f;
    f16x8 aq[4];
    {
        long rix = (long)(b * Qc + i0 + wave * 16 + lrow) * 1024 + n * 64;
        f16x8 q0 = *(const f16x8*)&qh[rix + quad * 8] * qsc;
        f16x8 q1 = *(const f16x8*)&qh[rix + 32 + quad * 8] * qsc;
        aq[0] = q0 + rw0;   // k-dim [0,32):  (q + r_w_bias) * scale, dot kh
        aq[1] = q1 + rw1;   // k-dim [32,64)
        aq[2] = q0;         // k-dim [64,96):  q * scale, dot Ke
        aq[3] = q1;         // k-dim [96,128)
    }

    float m_i = -1e30f, l_i = 0.0f;   // m: log2 domain, q-group uniform; l: per-lane partial
    f32x4 o_acc[4] = {};   // D[m=q][n=d]: row q=quad*4+reg, col d=lane&15

    // prologue: stage tile 0 (async) + rb0
    {
        float rbv = 0.0f;
        if (tid < 64) rbv = r_bias[(tid + 1) * Nh + n] * (ATT_SCALE * LOG2E);
        __builtin_amdgcn_global_load_lds((const AS1 void*)srcK, (AS3 void*)&sKa[0][wave * 512], 16, 0, 0);
        __builtin_amdgcn_global_load_lds((const AS1 void*)srcE, (AS3 void*)&sKe[0][wave * 512], 16, 0, 0);
        __builtin_amdgcn_global_load_lds((const AS1 void*)srcV, (AS3 void*)&sVa[0][wave * 512], 16, 0, 0);
        if (tid < 64) sRB[0][tid] = rbv;
    }
    __syncthreads();   // drains vmcnt(0): tile 0 resident

    for (int jt = 0; jt < 16; ++jt) {
        const int cur = jt & 1;

        // issue next tile's async loads FIRST (in flight across compute below)
        float rbn = 0.0f;
        if (jt < 15) {
            const int j0n = (jt + 1) * 64;
            __builtin_amdgcn_global_load_lds((const AS1 void*)(srcK + (long)j0n * 1024),
                                             (AS3 void*)&sKa[cur ^ 1][wave * 512], 16, 0, 0);
            __builtin_amdgcn_global_load_lds((const AS1 void*)(srcE + (long)j0n * 64),
                                             (AS3 void*)&sKe[cur ^ 1][wave * 512], 16, 0, 0);
            __builtin_amdgcn_global_load_lds((const AS1 void*)(srcV + j0n),
                                             (AS3 void*)&sVa[cur ^ 1][wave * 512], 16, 0, 0);
            if (tid < 64) {
                int j = j0n + tid;
                rbn = (j < Qc - 1) ? r_bias[(j + 1) * Nh + n] * (ATT_SCALE * LOG2E) : 0.0f;
            }
        }

        const f16* Ka = &sKa[cur][0];
        const f16* Kb = &sKe[cur][0];
        const f16* Va = &sVa[cur][0];
        const int rsw = lrow & 7;

        // S^T: D[m=j][n=q], 64 j x 16 q per wave; K=128 (kh | Ke)
        f32x4 s_acc[4] = {};
#pragma unroll
        for (int ni = 0; ni < 4; ++ni) {
            int rb_ = (ni * 16 + lrow) * 64;
            f16x8 a0 = *(const f16x8*)&Ka[rb_ + ((0 + quad) ^ rsw) * 8];
            f16x8 a1 = *(const f16x8*)&Ka[rb_ + ((4 + quad) ^ rsw) * 8];
            f16x8 e0 = *(const f16x8*)&Kb[rb_ + ((0 + quad) ^ rsw) * 8];
            f16x8 e1 = *(const f16x8*)&Kb[rb_ + ((4 + quad) ^ rsw) * 8];
            s_acc[ni] = __builtin_amdgcn_mfma_f32_16x16x32_f16(a0, aq[0], s_acc[ni], 0, 0, 0);
            s_acc[ni] = __builtin_amdgcn_mfma_f32_16x16x32_f16(a1, aq[1], s_acc[ni], 0, 0, 0);
            s_acc[ni] = __builtin_amdgcn_mfma_f32_16x16x32_f16(e0, aq[2], s_acc[ni], 0, 0, 0);
            s_acc[ni] = __builtin_amdgcn_mfma_f32_16x16x32_f16(e1, aq[3], s_acc[ni], 0, 0, 0);
        }

        // speculative online softmax (log2 domain): P = exp2(v - m_old) fused
        // with the max scan; rescale path only when the wave-uniform test fires.
        f16x4 pf[4];
        float mx = -1e30f, sm = 0.0f;
#pragma unroll
        for (int ni = 0; ni < 4; ++ni) {
            f32x4 rb4 = *(const f32x4*)&sRB[cur][ni * 16 + quad * 4];
            f16x4 pvv;
#pragma unroll
            for (int r = 0; r < 4; ++r) {
                float v = fmaf(s_acc[ni][r], LOG2E, rb4[r]);
                s_acc[ni][r] = v;
                mx = fmaxf(mx, v);
                float e = __builtin_amdgcn_exp2f(v - m_i);
                sm += e;
                pvv[r] = (f16)e;
            }
            pf[ni] = pvv;
        }
        if (!__all(mx - m_i <= 8.0f)) {
            float wmx = fmaxf(mx, __shfl_xor(mx, 16));
            wmx = fmaxf(wmx, __shfl_xor(wmx, 32));
            float mn = fmaxf(m_i, wmx);            // q-group uniform
            float alpha = __builtin_amdgcn_exp2f(m_i - mn);   // q-group uniform
            sm = 0.0f;
#pragma unroll
            for (int ni = 0; ni < 4; ++ni) {
                f16x4 pvv;
#pragma unroll
                for (int r = 0; r < 4; ++r) {
                    float e = __builtin_amdgcn_exp2f(s_acc[ni][r] - mn);
                    sm += e;
                    pvv[r] = (f16)e;
                }
                pf[ni] = pvv;
            }
            l_i *= alpha;   // uniform scaling keeps per-lane partials consistent
#pragma unroll
            for (int r = 0; r < 4; ++r) {
                float al = __shfl(alpha, quad * 4 + r);
#pragma unroll
                for (int dt = 0; dt < 4; ++dt) o_acc[dt][r] *= al;
            }
            m_i = mn;
        }
        l_i += sm;

        // PV: D[m=q][n=d] += P[q][j] * V[j][d], K=16 chunks, P from registers.
        // sVa read with source-matched swizzle (16B chunk ^ (d&7)).
#pragma unroll
        for (int nj = 0; nj < 4; ++nj) {
            int coff = ((2 * nj + (quad >> 1)) ^ rsw) * 8 + (quad & 1) * 4;
#pragma unroll
            for (int dt = 0; dt < 4; ++dt) {
                f16x4 bv = *(const f16x4*)&Va[(dt * 16 + lrow) * 64 + coff];
                o_acc[dt] = __builtin_amdgcn_mfma_f32_16x16x16f16(pf[nj], bv, o_acc[dt], 0, 0, 0);
            }
        }

        if (jt < 15) {
            if (tid < 64) sRB[cur ^ 1][tid] = rbn;
            __syncthreads();   // drains vmcnt: next tile resident; rb visible
        }
    }

    // epilogue: deferred cross-lane l reduction (valid: all partials share the
    // same q-group-uniform m scaling), then avp = O / l.
    l_i += __shfl_xor(l_i, 16);
    l_i += __shfl_xor(l_i, 32);
    {
        float linv = 1.0f / l_i;
#pragma unroll
        for (int r = 0; r < 4; ++r) {
            float li = __shfl(linv, quad * 4 + r);
            int i = i0 + wave * 16 + quad * 4 + r;
#pragma unroll
            for (int dt = 0; dt < 4; ++dt) {
                int d = dt * 16 + lrow;
                avp[((long)(b * Qc + i) << 10) + n * 64 + d] = (f16)(o_acc[dt][r] * li);
            }
        }
    }
}

// ---------------- residual + LayerNorm (w f32, ao f16; f32 output) ----------------
__global__ __launch_bounds__(256) void k_res_ln(const float* __restrict__ w, const f16* __restrict__ ao,
                                                const float* __restrict__ gamma, const float* __restrict__ beta,
                                                float* __restrict__ out) {
    const long base = (long)blockIdx.x * 1024;
    const int tid = threadIdx.x;
    float4 wv = *(const float4*)&w[base + tid * 4];
    f16x4 av = *(const f16x4*)&ao[base + tid * 4];
    float x[4] = { wv.x + (float)av[0], wv.y + (float)av[1],
                   wv.z + (float)av[2], wv.w + (float)av[3] };
    float s = x[0] + x[1] + x[2] + x[3];
    float s2 = x[0] * x[0] + x[1] * x[1] + x[2] * x[2] + x[3] * x[3];
#pragma unroll
    for (int off = 32; off; off >>= 1) { s += __shfl_down(s, off); s2 += __shfl_down(s2, off); }
    __shared__ float rs[4], rs2[4];
    if ((tid & 63) == 0) { rs[tid >> 6] = s; rs2[tid >> 6] = s2; }
    __syncthreads();
    s = rs[0] + rs[1] + rs[2] + rs[3];
    s2 = rs2[0] + rs2[1] + rs2[2] + rs2[3];
    float mu = s * (1.0f / 1024.0f);
    float var = s2 * (1.0f / 1024.0f) - mu * mu;
    float inv = rsqrtf(var + 1e-5f);
    float4 gv = *(const float4*)&gamma[tid * 4];
    float4 bv = *(const float4*)&beta[tid * 4];
    float4 o;
    o.x = (x[0] - mu) * inv * gv.x + bv.x;
    o.y = (x[1] - mu) * inv * gv.y + bv.y;
    o.z = (x[2] - mu) * inv * gv.z + bv.z;
    o.w = (x[3] - mu) * inv * gv.w + bv.w;
    *(float4*)&out[base + tid * 4] = o;
}

extern "C" void kernel_launch(void* const* d_in, const int* in_sizes, int n_in,
                              void* d_out, int out_size, void* d_ws, size_t ws_size,
                              hipStream_t stream) {
    const float* w_in   = (const float*)d_in[0];
    const float* r_emb  = (const float*)d_in[1];
    const float* r_wb   = (const float*)d_in[2];
    const float* r_bias = (const float*)d_in[3];
    const float* Wq     = (const float*)d_in[4];
    const float* Wk     = (const float*)d_in[5];
    const float* Wv     = (const float*)d_in[6];
    const float* Wo     = (const float*)d_in[7];
    const float* ln_g   = (const float*)d_in[8];
    const float* ln_b   = (const float*)d_in[9];
    float* out = (float*)d_out;

    // workspace carve-out (48MB fixed + aliases)
    char* p = (char*)d_ws;
    auto alloc = [&](size_t bytes) { char* r = p; p += (bytes + 255) & ~(size_t)255; return r; };
    f16* wh = (f16*)alloc((size_t)BQ * Dc * 2);          // 8 MB
    f16* WT = (f16*)alloc((size_t)4 * Dc * Dc * 2);      // 8 MB: WqT,WkT,WvT,WoT (contiguous)
    f16* qh = (f16*)alloc((size_t)BQ * Dc * 2);          // 8 MB [b*Q+i][n*64+d]
    f16* kh = (f16*)alloc((size_t)BQ * Dc * 2);          // 8 MB [b*Q+j][n*64+d]
    f16* Ke = (f16*)alloc((size_t)NHEAD * Qc * DHc * 2); // 8 MB [h][j][64] rel-shifted r_emb
    f16* vT = (f16*)alloc((size_t)BQ * Dc * 2);          // 8 MB [b][dcol][j]
    f16* WoT = WT + (size_t)3 * Dc * Dc;
    // aliases (liveness-checked): wh dead after QKV GEMM; Ke dead after flash
    f16* avp = wh;                 // [b][i][1024] f16
    f16* ao  = Ke;                 // 8 MB f16

    // 1. merged preprocessing: f2h + weight transpose + Ke fill (one dispatch)
    Ptr4 srcs{{Wq, Wk, Wv, Wo}};
    k_prep<<<8192, 256, 0, stream>>>(w_in, wh, srcs, WT, r_emb, Ke);

    // 2. fused QKV projection: 64x128 tile -> dim3(24,64) = 1536 blocks = 6/CU
    k_gemm_nt<64, 128, 32, 2, 2, 5><<<dim3(3 * Dc / 128, BQ / 64), 256, 0, stream>>>(
        wh, WT, nullptr, qh, kh, vT, Dc, Dc, 0, Dc);

    // 3. fused attention (XCD-swizzled 1D grid 512, 8-wave blocks, async dbuf)
    k_flash<<<512, 512, 0, stream>>>(qh, kh, Ke, vT, r_wb, r_bias, avp);

    // 4. attn_out = avp @ Wo^T (64x64 tile -> dim3(16,64) = 1024 blocks = 4/CU)
    k_gemm_nt<64, 64, 32, 2, 2, 0><<<dim3(Dc / 64, BQ / 64), 256, 0, stream>>>(
        avp, WoT, ao, nullptr, nullptr, nullptr, Dc, Dc, Dc, Dc);

    // 5. out = LayerNorm(w + attn_out), fp32 output
    k_res_ln<<<BQ, 256, 0, stream>>>(w_in, ao, ln_g, ln_b, out);
}

// Round 13
// 211.549 us; speedup vs baseline: 1.0046x; 1.0046x over previous
//
#include <hip/hip_runtime.h>
#include <hip/hip_bf16.h>

using f16 = _Float16;
typedef _Float16 f16x8 __attribute__((ext_vector_type(8)));
typedef _Float16 f16x4 __attribute__((ext_vector_type(4)));
typedef float f32x4 __attribute__((ext_vector_type(4)));

#define AS1 __attribute__((address_space(1)))
#define AS3 __attribute__((address_space(3)))

// Problem constants
constexpr int Bc = 4, Qc = 1024, Dc = 1024, Nh = 16, DHc = 64;
constexpr int BQ = Bc * Qc;      // 4096 rows of w
constexpr int NHEAD = Bc * Nh;   // 64 (b,n) heads
constexpr float ATT_SCALE = 0.125f;
constexpr float LOG2E = 1.44269504088896f;

// ---------------- merged preprocessing: f2h | 4-way transpose | rel-shift r_emb ----------------
struct Ptr4 { const float* p[4]; };
__global__ __launch_bounds__(256) void k_prep(
    const float* __restrict__ w_in, f16* __restrict__ wh,
    Ptr4 srcs, f16* __restrict__ WT,
    const float* __restrict__ remb, f16* __restrict__ Ke)
{
    const int bid = blockIdx.x, tid = threadIdx.x;
    if (bid < 2048) {
        long i8 = ((long)bid * 256 + tid) * 8;
        float4 a = *(const float4*)&w_in[i8];
        float4 b = *(const float4*)&w_in[i8 + 4];
        f16x8 o = { (f16)a.x, (f16)a.y, (f16)a.z, (f16)a.w,
                    (f16)b.x, (f16)b.y, (f16)b.z, (f16)b.w };
        *(f16x8*)&wh[i8] = o;
    } else if (bid < 6144) {
        __shared__ f16 tile[32][33];
        int idx = bid - 2048;
        int z = idx >> 10, rem = idx & 1023;
        int r0 = (rem >> 5) * 32, c0 = (rem & 31) * 32;
        const float* src = srcs.p[z];
        f16* d = WT + (long)z * Dc * Dc;
        int tx = tid & 31, ty = tid >> 5;   // 32 x 8
#pragma unroll
        for (int dy = 0; dy < 32; dy += 8) {
            int r = r0 + ty + dy, c = c0 + tx;
            tile[ty + dy][tx] = (f16)src[(long)r * Dc + c];
        }
        __syncthreads();
#pragma unroll
        for (int dy = 0; dy < 32; dy += 8) {
            int c = c0 + ty + dy, r = r0 + tx;
            d[(long)c * Dc + r] = tile[tx][ty + dy];
        }
    } else {
        long gid = (long)(bid - 6144) * 256 + tid;  // 64*1024*8
        int d8 = (int)(gid & 7) * 8;
        int j = (int)((gid >> 3) & 1023);
        int h = (int)(gid >> 13);
        int n = h & 15;
        f16x8 kv;
        if (j < 1023) {
            const float* rp = &remb[((long)(j + 1) * 16 + n) * 64 + d8];
            float4 r0 = *(const float4*)rp, r1 = *(const float4*)(rp + 4);
            kv[0] = (f16)r0.x; kv[1] = (f16)r0.y; kv[2] = (f16)r0.z; kv[3] = (f16)r0.w;
            kv[4] = (f16)r1.x; kv[5] = (f16)r1.y; kv[6] = (f16)r1.z; kv[7] = (f16)r1.w;
        } else {
            kv = f16x8{};
        }
        *(f16x8*)&Ke[(((long)h << 10) + j) * 64 + d8] = kv;
    }
}

// ---------------- NT GEMM (R8-proven BK=64 body) + fused K'/ck epilogue ----------------
// R12 reverted: fine tiles doubled B-panel HBM traffic (FETCH 28.8->49.5MB) and
// fell to 425 TF; occupancy was NOT the binding constraint. Back to BM=128/BK=64
// (R6/R8, QKV ~41us, conflicts==0).
// NEW (EPI==5, seg==1): algebraic fold (q+rwb)·k + q·ke = q·(k+ke) + rwb·k.
// Epilogue writes ktp = val + Ke (K' operand, halves flash's S^T K-dim) and
// reduces ck[row] = sum val*rwb over the wave's 64-col head segment (4x
// shfl_xor over ccol), storing CKRB = (ck + rb_shifted)*ATT_SCALE*LOG2E for
// flash's per-j bias. rwb·k now f32 x f32 (better than old f16 path).
// Tripwires: conflicts == 0, absmax <= 0.108 (expect 0.03-0.06; fail -> ck/Ke
// indexing bug, fallback R8 verbatim).
template <int BM, int BN, int BK, int WROWS, int WCOLS, int EPI>
__global__ __launch_bounds__(256) void k_gemm_nt(
    const f16* __restrict__ A, const f16* __restrict__ Bt, void* __restrict__ Cv,
    f16* __restrict__ qtp, f16* __restrict__ ktp, f16* __restrict__ vtp,
    const float* __restrict__ rwb, const float* __restrict__ rbias,
    const f16* __restrict__ KeAdd, float* __restrict__ ckrb,
    int lda, int ldb, int ldc, int K)
{
    static_assert(BK == 64, "geometry below assumes BK=64");
    constexpr int TM = BM / (WROWS * 16);
    constexpr int TN = BN / (WCOLS * 16);
    __shared__ __align__(16) f16 sA[BM * 64];
    __shared__ __align__(16) f16 sB[BN * 64];

    const int tid = threadIdx.x;
    const int lane = tid & 63, wave = tid >> 6;
    const int wm = wave / WCOLS, wn = wave % WCOLS;

    const int nwg = gridDim.x * gridDim.y;
    const int flat = blockIdx.y * gridDim.x + blockIdx.x;
    const int cpx = nwg >> 3;
    const int swz = (flat & 7) * cpx + (flat >> 3);
    const int bx = swz % gridDim.x, by = swz / gridDim.x;
    const int m0 = by * BM, n0 = bx * BN;

    f32x4 acc[TM][TN] = {};

    const int lrow = lane & 15;
    const int quad = lane >> 4;
    const int srow = lane >> 3;            // row within 1KB chunk (0..7)
    const int scol = ((lane & 7) ^ (srow & 7)) * 8;   // inverse-swizzled src chunk

    for (int k0 = 0; k0 < K; k0 += 64) {
        __syncthreads();
        constexpr int CHA = BM / 8;   // 1KB chunks per A tile
#pragma unroll
        for (int ch = 0; ch < CHA / 4; ++ch) {
            int cc = ch * 4 + wave;
            __builtin_amdgcn_global_load_lds(
                (const AS1 void*)(const void*)&A[(long)(m0 + cc * 8 + srow) * lda + k0 + scol],
                (AS3 void*)(void*)&sA[cc * 512], 16, 0, 0);
        }
        constexpr int CHB = BN / 8;
#pragma unroll
        for (int ch = 0; ch < CHB / 4; ++ch) {
            int cc = ch * 4 + wave;
            __builtin_amdgcn_global_load_lds(
                (const AS1 void*)(const void*)&Bt[(long)(n0 + cc * 8 + srow) * ldb + k0 + scol],
                (AS3 void*)(void*)&sB[cc * 512], 16, 0, 0);
        }
        __syncthreads();

        // two K=32 slices per staged 64-col tile; swizzled chunk = kc ^ (row&7)
#pragma unroll
        for (int kk = 0; kk < 2; ++kk) {
            const int kcb = kk * 4 + quad;   // global 16B-chunk index (0..7)
            f16x8 af[TM], bfr[TN];
#pragma unroll
            for (int mi = 0; mi < TM; ++mi) {
                int R = wm * TM * 16 + mi * 16 + lrow;
                af[mi] = *(const f16x8*)&sA[R * 64 + ((kcb ^ (lrow & 7)) * 8)];
            }
#pragma unroll
            for (int ni = 0; ni < TN; ++ni) {
                int R = wn * TN * 16 + ni * 16 + lrow;
                bfr[ni] = *(const f16x8*)&sB[R * 64 + ((kcb ^ (lrow & 7)) * 8)];
            }
#pragma unroll
            for (int mi = 0; mi < TM; ++mi)
#pragma unroll
                for (int ni = 0; ni < TN; ++ni)
                    acc[mi][ni] = __builtin_amdgcn_mfma_f32_16x16x32_f16(af[mi], bfr[ni], acc[mi][ni], 0, 0, 0);
        }
    }

    const int crow = (lane >> 4) * 4;
    const int ccol = lane & 15;

    if constexpr (EPI == 5) {
        int seg = n0 >> 10;
        if (seg == 1) {
            // fused K'-write + ck row-dot (wave covers 64 rows x one head's 64 cols)
            const int hn = ((n0 & 1023) + wn * TN * 16) >> 6;   // head 0..15
            float rwbl[TN];
#pragma unroll
            for (int ni = 0; ni < TN; ++ni)
                rwbl[ni] = rwb[hn * 64 + ni * 16 + ccol];
#pragma unroll
            for (int mi = 0; mi < TM; ++mi)
#pragma unroll
                for (int r = 0; r < 4; ++r) {
                    int gm = m0 + wm * TM * 16 + mi * 16 + crow + r;
                    int bb = gm >> 10, j = gm & 1023;
                    long kebase = (((long)(bb * 16 + hn) << 10) + j) * 64;
                    float dot = 0.0f;
#pragma unroll
                    for (int ni = 0; ni < TN; ++ni) {
                        float val = acc[mi][ni][r];
                        dot += val * rwbl[ni];
                        int d = ni * 16 + ccol;
                        ktp[(long)gm * 1024 + hn * 64 + d] =
                            (f16)(val + (float)KeAdd[kebase + d]);
                    }
                    dot += __shfl_xor(dot, 1);
                    dot += __shfl_xor(dot, 2);
                    dot += __shfl_xor(dot, 4);
                    dot += __shfl_xor(dot, 8);
                    if (ccol == 0) {
                        float rbv = (j < 1023) ? rbias[(j + 1) * 16 + hn] : 0.0f;
                        ckrb[(((long)(bb * 16 + hn)) << 10) + j] =
                            (dot + rbv) * (ATT_SCALE * LOG2E);
                    }
                }
            return;
        }
    }

#pragma unroll
    for (int mi = 0; mi < TM; ++mi)
#pragma unroll
        for (int ni = 0; ni < TN; ++ni)
#pragma unroll
            for (int r = 0; r < 4; ++r) {
                int gm = m0 + wm * TM * 16 + mi * 16 + crow + r;
                int gn = n0 + wn * TN * 16 + ni * 16 + ccol;
                float val = acc[mi][ni][r];
                if constexpr (EPI == 0) {
                    ((f16*)Cv)[(long)gm * ldc + gn] = (f16)val;
                } else {
                    int seg = n0 >> 10;       // block-uniform (seg 0 or 2 here)
                    int col = gn & 1023;
                    if (seg == 0) {
                        qtp[(long)gm * 1024 + col] = (f16)val;
                    } else {
                        int b = gm >> 10, i = gm & 1023;
                        vtp[(((long)(b << 10) + col) << 10) + i] = (f16)val;
                    }
                }
            }
}

// ---------------- fused flash attention v16: K-folded (K'=k+ke, ck in bias).
// S = q·K' + (rwb·k + rb) -> S^T K-dim halves 128->64: 8 MFMA/iter (was 16),
// staging 3->2 streams, LDS 49.6->33KB. Bias stream is the precomputed CKRB
// (already *ATT_SCALE*LOG2E). Softmax/PV/defer-max unchanged from v13 (47.1us,
// no setprio per R11 A/B). Tripwires: WRITE == 8192 KB, FETCH ~11-13MB,
// VGPR <= 64, absmax <= 0.108 (expect 0.03-0.06).
__global__ __launch_bounds__(512, 4) void k_flash(
    const f16* __restrict__ qh, const f16* __restrict__ kh,
    const f16* __restrict__ vT, const float* __restrict__ ckrb,
    f16* __restrict__ avp)
{
    __shared__ __align__(16) f16 sKa[2][64 * 64];   // K' tile: [j-local][d]
    __shared__ __align__(16) f16 sVa[2][64 * 64];   // vT tile: [d][j-local]
    __shared__ float sRB[2][64];

    const int tid = threadIdx.x, lane = tid & 63, wave = tid >> 6;  // wave 0..7
    const int bid = blockIdx.x;
    const int h = (((bid >> 3) & 7) << 3) | (bid & 7);
    const int i0 = (bid >> 6) * 128;
    const int b = h >> 4, n = h & 15;

    const int lrow = lane & 15;            // q (B-frag n) / row index
    const int quad = lane >> 4;
    const int lr3 = lane >> 3;             // staging: row within wave's 8-row slice
    const int swc = (lane & 7) ^ (lr3 & 7);  // inverse-swizzled source 16B chunk

    // wave-slice per-lane source pointers (tile row = 8*wave + lr3)
    const f16* srcK = kh + ((long)(b * Qc) + 8 * wave + lr3) * 1024 + n * 64 + swc * 8;
    const f16* srcV = vT + (long)h * DHc * Qc + (long)(8 * wave + lr3) * Qc + swc * 8;

    // Q fragments (B-operand of S^T): wave owns q rows [i0+wave*16, +16).
    const f16 qsc = (f16)0.125f;
    f16x8 aq[2];
    {
        long rix = (long)(b * Qc + i0 + wave * 16 + lrow) * 1024 + n * 64;
        aq[0] = *(const f16x8*)&qh[rix + quad * 8] * qsc;        // k-dim [0,32)
        aq[1] = *(const f16x8*)&qh[rix + 32 + quad * 8] * qsc;   // k-dim [32,64)
    }

    float m_i = -1e30f, l_i = 0.0f;   // m: log2 domain, q-group uniform; l: per-lane partial
    f32x4 o_acc[4] = {};   // D[m=q][n=d]: row q=quad*4+reg, col d=lane&15

    // prologue: stage tile 0 (async) + rb0
    {
        float rbv = 0.0f;
        if (tid < 64) rbv = ckrb[((long)h << 10) + tid];
        __builtin_amdgcn_global_load_lds((const AS1 void*)srcK, (AS3 void*)&sKa[0][wave * 512], 16, 0, 0);
        __builtin_amdgcn_global_load_lds((const AS1 void*)srcV, (AS3 void*)&sVa[0][wave * 512], 16, 0, 0);
        if (tid < 64) sRB[0][tid] = rbv;
    }
    __syncthreads();   // drains vmcnt(0): tile 0 resident

    for (int jt = 0; jt < 16; ++jt) {
        const int cur = jt & 1;

        // issue next tile's async loads FIRST (in flight across compute below)
        float rbn = 0.0f;
        if (jt < 15) {
            const int j0n = (jt + 1) * 64;
            __builtin_amdgcn_global_load_lds((const AS1 void*)(srcK + (long)j0n * 1024),
                                             (AS3 void*)&sKa[cur ^ 1][wave * 512], 16, 0, 0);
            __builtin_amdgcn_global_load_lds((const AS1 void*)(srcV + j0n),
                                             (AS3 void*)&sVa[cur ^ 1][wave * 512], 16, 0, 0);
            if (tid < 64) rbn = ckrb[((long)h << 10) + j0n + tid];
        }

        const f16* Ka = &sKa[cur][0];
        const f16* Va = &sVa[cur][0];
        const int rsw = lrow & 7;

        // S^T: D[m=j][n=q], 64 j x 16 q per wave; K=64 (K' = k+ke)
        f32x4 s_acc[4] = {};
#pragma unroll
        for (int ni = 0; ni < 4; ++ni) {
            int rb_ = (ni * 16 + lrow) * 64;
            f16x8 a0 = *(const f16x8*)&Ka[rb_ + ((0 + quad) ^ rsw) * 8];
            f16x8 a1 = *(const f16x8*)&Ka[rb_ + ((4 + quad) ^ rsw) * 8];
            s_acc[ni] = __builtin_amdgcn_mfma_f32_16x16x32_f16(a0, aq[0], s_acc[ni], 0, 0, 0);
            s_acc[ni] = __builtin_amdgcn_mfma_f32_16x16x32_f16(a1, aq[1], s_acc[ni], 0, 0, 0);
        }

        // speculative online softmax (log2 domain): P = exp2(v - m_old) fused
        // with the max scan; rescale path only when the wave-uniform test fires.
        f16x4 pf[4];
        float mx = -1e30f, sm = 0.0f;
#pragma unroll
        for (int ni = 0; ni < 4; ++ni) {
            f32x4 rb4 = *(const f32x4*)&sRB[cur][ni * 16 + quad * 4];
            f16x4 pvv;
#pragma unroll
            for (int r = 0; r < 4; ++r) {
                float v = fmaf(s_acc[ni][r], LOG2E, rb4[r]);
                s_acc[ni][r] = v;
                mx = fmaxf(mx, v);
                float e = __builtin_amdgcn_exp2f(v - m_i);
                sm += e;
                pvv[r] = (f16)e;
            }
            pf[ni] = pvv;
        }
        if (!__all(mx - m_i <= 8.0f)) {
            float wmx = fmaxf(mx, __shfl_xor(mx, 16));
            wmx = fmaxf(wmx, __shfl_xor(wmx, 32));
            float mn = fmaxf(m_i, wmx);            // q-group uniform
            float alpha = __builtin_amdgcn_exp2f(m_i - mn);   // q-group uniform
            sm = 0.0f;
#pragma unroll
            for (int ni = 0; ni < 4; ++ni) {
                f16x4 pvv;
#pragma unroll
                for (int r = 0; r < 4; ++r) {
                    float e = __builtin_amdgcn_exp2f(s_acc[ni][r] - mn);
                    sm += e;
                    pvv[r] = (f16)e;
                }
                pf[ni] = pvv;
            }
            l_i *= alpha;   // uniform scaling keeps per-lane partials consistent
#pragma unroll
            for (int r = 0; r < 4; ++r) {
                float al = __shfl(alpha, quad * 4 + r);
#pragma unroll
                for (int dt = 0; dt < 4; ++dt) o_acc[dt][r] *= al;
            }
            m_i = mn;
        }
        l_i += sm;

        // PV: D[m=q][n=d] += P[q][j] * V[j][d], K=16 chunks, P from registers.
        // sVa read with source-matched swizzle (16B chunk ^ (d&7)).
#pragma unroll
        for (int nj = 0; nj < 4; ++nj) {
            int coff = ((2 * nj + (quad >> 1)) ^ rsw) * 8 + (quad & 1) * 4;
#pragma unroll
            for (int dt = 0; dt < 4; ++dt) {
                f16x4 bv = *(const f16x4*)&Va[(dt * 16 + lrow) * 64 + coff];
                o_acc[dt] = __builtin_amdgcn_mfma_f32_16x16x16f16(pf[nj], bv, o_acc[dt], 0, 0, 0);
            }
        }

        if (jt < 15) {
            if (tid < 64) sRB[cur ^ 1][tid] = rbn;
            __syncthreads();   // drains vmcnt: next tile resident; rb visible
        }
    }

    // epilogue: deferred cross-lane l reduction (valid: all partials share the
    // same q-group-uniform m scaling), then avp = O / l.
    l_i += __shfl_xor(l_i, 16);
    l_i += __shfl_xor(l_i, 32);
    {
        float linv = 1.0f / l_i;
#pragma unroll
        for (int r = 0; r < 4; ++r) {
            float li = __shfl(linv, quad * 4 + r);
            int i = i0 + wave * 16 + quad * 4 + r;
#pragma unroll
            for (int dt = 0; dt < 4; ++dt) {
                int d = dt * 16 + lrow;
                avp[((long)(b * Qc + i) << 10) + n * 64 + d] = (f16)(o_acc[dt][r] * li);
            }
        }
    }
}

// ---------------- residual + LayerNorm (w f32, ao f16; f32 output) ----------------
__global__ __launch_bounds__(256) void k_res_ln(const float* __restrict__ w, const f16* __restrict__ ao,
                                                const float* __restrict__ gamma, const float* __restrict__ beta,
                                                float* __restrict__ out) {
    const long base = (long)blockIdx.x * 1024;
    const int tid = threadIdx.x;
    float4 wv = *(const float4*)&w[base + tid * 4];
    f16x4 av = *(const f16x4*)&ao[base + tid * 4];
    float x[4] = { wv.x + (float)av[0], wv.y + (float)av[1],
                   wv.z + (float)av[2], wv.w + (float)av[3] };
    float s = x[0] + x[1] + x[2] + x[3];
    float s2 = x[0] * x[0] + x[1] * x[1] + x[2] * x[2] + x[3] * x[3];
#pragma unroll
    for (int off = 32; off; off >>= 1) { s += __shfl_down(s, off); s2 += __shfl_down(s2, off); }
    __shared__ float rs[4], rs2[4];
    if ((tid & 63) == 0) { rs[tid >> 6] = s; rs2[tid >> 6] = s2; }
    __syncthreads();
    s = rs[0] + rs[1] + rs[2] + rs[3];
    s2 = rs2[0] + rs2[1] + rs2[2] + rs2[3];
    float mu = s * (1.0f / 1024.0f);
    float var = s2 * (1.0f / 1024.0f) - mu * mu;
    float inv = rsqrtf(var + 1e-5f);
    float4 gv = *(const float4*)&gamma[tid * 4];
    float4 bv = *(const float4*)&beta[tid * 4];
    float4 o;
    o.x = (x[0] - mu) * inv * gv.x + bv.x;
    o.y = (x[1] - mu) * inv * gv.y + bv.y;
    o.z = (x[2] - mu) * inv * gv.z + bv.z;
    o.w = (x[3] - mu) * inv * gv.w + bv.w;
    *(float4*)&out[base + tid * 4] = o;
}

extern "C" void kernel_launch(void* const* d_in, const int* in_sizes, int n_in,
                              void* d_out, int out_size, void* d_ws, size_t ws_size,
                              hipStream_t stream) {
    const float* w_in   = (const float*)d_in[0];
    const float* r_emb  = (const float*)d_in[1];
    const float* r_wb   = (const float*)d_in[2];
    const float* r_bias = (const float*)d_in[3];
    const float* Wq     = (const float*)d_in[4];
    const float* Wk     = (const float*)d_in[5];
    const float* Wv     = (const float*)d_in[6];
    const float* Wo     = (const float*)d_in[7];
    const float* ln_g   = (const float*)d_in[8];
    const float* ln_b   = (const float*)d_in[9];
    float* out = (float*)d_out;

    // workspace carve-out (48.25MB fixed + aliases)
    char* p = (char*)d_ws;
    auto alloc = [&](size_t bytes) { char* r = p; p += (bytes + 255) & ~(size_t)255; return r; };
    f16* wh = (f16*)alloc((size_t)BQ * Dc * 2);          // 8 MB
    f16* WT = (f16*)alloc((size_t)4 * Dc * Dc * 2);      // 8 MB: WqT,WkT,WvT,WoT (contiguous)
    f16* qh = (f16*)alloc((size_t)BQ * Dc * 2);          // 8 MB [b*Q+i][n*64+d]
    f16* kh = (f16*)alloc((size_t)BQ * Dc * 2);          // 8 MB [b*Q+j][n*64+d] -> K' after QKV
    f16* Ke = (f16*)alloc((size_t)NHEAD * Qc * DHc * 2); // 8 MB [h][j][64] rel-shifted r_emb
    f16* vT = (f16*)alloc((size_t)BQ * Dc * 2);          // 8 MB [b][dcol][j]
    float* ckrb = (float*)alloc((size_t)NHEAD * Qc * 4); // 256 KB (rwb·k + rb)*scale*log2e
    f16* WoT = WT + (size_t)3 * Dc * Dc;
    // aliases (liveness-checked): wh dead after QKV GEMM; Ke dead after QKV GEMM
    f16* avp = wh;                 // [b][i][1024] f16
    f16* ao  = Ke;                 // 8 MB f16

    // 1. merged preprocessing: f2h + weight transpose + Ke fill (one dispatch)
    Ptr4 srcs{{Wq, Wk, Wv, Wo}};
    k_prep<<<8192, 256, 0, stream>>>(w_in, wh, srcs, WT, r_emb, Ke);

    // 2. fused QKV projection + K'/ck epilogue: dim3(24,32), BM=128/BK=64
    k_gemm_nt<128, 128, 64, 2, 2, 5><<<dim3(3 * Dc / 128, BQ / 128), 256, 0, stream>>>(
        wh, WT, nullptr, qh, kh, vT, r_wb, r_bias, Ke, ckrb, Dc, Dc, 0, Dc);

    // 3. fused attention (XCD-swizzled 1D grid 512, 8-wave blocks, async dbuf, K=64)
    k_flash<<<512, 512, 0, stream>>>(qh, kh, vT, ckrb, avp);

    // 4. attn_out = avp @ Wo^T (64x128 tile -> 512 blocks; f16 out into aliased ao)
    k_gemm_nt<64, 128, 64, 2, 2, 0><<<dim3(Dc / 128, BQ / 64), 256, 0, stream>>>(
        avp, WoT, ao, nullptr, nullptr, nullptr, nullptr, nullptr, nullptr, nullptr,
        Dc, Dc, Dc, Dc);

    // 5. out = LayerNorm(w + attn_out), fp32 output
    k_res_ln<<<BQ, 256, 0, stream>>>(w_in, ao, ln_g, ln_b, out);
}

// Round 14
// 207.527 us; speedup vs baseline: 1.0241x; 1.0194x over previous
//
#include <hip/hip_runtime.h>
#include <hip/hip_bf16.h>

using f16 = _Float16;
typedef _Float16 f16x8 __attribute__((ext_vector_type(8)));
typedef _Float16 f16x4 __attribute__((ext_vector_type(4)));
typedef float f32x4 __attribute__((ext_vector_type(4)));

#define AS1 __attribute__((address_space(1)))
#define AS3 __attribute__((address_space(3)))

// Problem constants
constexpr int Bc = 4, Qc = 1024, Dc = 1024, Nh = 16, DHc = 64;
constexpr int BQ = Bc * Qc;      // 4096 rows of w
constexpr int NHEAD = Bc * Nh;   // 64 (b,n) heads
constexpr float ATT_SCALE = 0.125f;
constexpr float LOG2E = 1.44269504088896f;

// ---------------- merged preprocessing: f2h | 4-way transpose | rel-shift r_emb ----------------
struct Ptr4 { const float* p[4]; };
__global__ __launch_bounds__(256) void k_prep(
    const float* __restrict__ w_in, f16* __restrict__ wh,
    Ptr4 srcs, f16* __restrict__ WT,
    const float* __restrict__ remb, f16* __restrict__ Ke)
{
    const int bid = blockIdx.x, tid = threadIdx.x;
    if (bid < 2048) {
        long i8 = ((long)bid * 256 + tid) * 8;
        float4 a = *(const float4*)&w_in[i8];
        float4 b = *(const float4*)&w_in[i8 + 4];
        f16x8 o = { (f16)a.x, (f16)a.y, (f16)a.z, (f16)a.w,
                    (f16)b.x, (f16)b.y, (f16)b.z, (f16)b.w };
        *(f16x8*)&wh[i8] = o;
    } else if (bid < 6144) {
        __shared__ f16 tile[32][33];
        int idx = bid - 2048;
        int z = idx >> 10, rem = idx & 1023;
        int r0 = (rem >> 5) * 32, c0 = (rem & 31) * 32;
        const float* src = srcs.p[z];
        f16* d = WT + (long)z * Dc * Dc;
        int tx = tid & 31, ty = tid >> 5;   // 32 x 8
#pragma unroll
        for (int dy = 0; dy < 32; dy += 8) {
            int r = r0 + ty + dy, c = c0 + tx;
            tile[ty + dy][tx] = (f16)src[(long)r * Dc + c];
        }
        __syncthreads();
#pragma unroll
        for (int dy = 0; dy < 32; dy += 8) {
            int c = c0 + ty + dy, r = r0 + tx;
            d[(long)c * Dc + r] = tile[tx][ty + dy];
        }
    } else {
        long gid = (long)(bid - 6144) * 256 + tid;  // 64*1024*8
        int d8 = (int)(gid & 7) * 8;
        int j = (int)((gid >> 3) & 1023);
        int h = (int)(gid >> 13);
        int n = h & 15;
        f16x8 kv;
        if (j < 1023) {
            const float* rp = &remb[((long)(j + 1) * 16 + n) * 64 + d8];
            float4 r0 = *(const float4*)rp, r1 = *(const float4*)(rp + 4);
            kv[0] = (f16)r0.x; kv[1] = (f16)r0.y; kv[2] = (f16)r0.z; kv[3] = (f16)r0.w;
            kv[4] = (f16)r1.x; kv[5] = (f16)r1.y; kv[6] = (f16)r1.z; kv[7] = (f16)r1.w;
        } else {
            kv = f16x8{};
        }
        *(f16x8*)&Ke[(((long)h << 10) + j) * 64 + d8] = kv;
    }
}

// ---------------- K-fold streaming kernel: kh += Ke (in place) + ckrb dot ----------------
// R13 lesson: doing this fold inside the GEMM epilogue cost +22us (scalar Ke
// loads -> FETCH 60MB, occupancy 14%). As a dedicated streaming pass it is
// ~24MB of perfectly-coalesced traffic (~4-6us): wave reads 1KB contiguous of
// kh (8 segs x 8 lanes x 16B), Ke in 128B chunks, writes back in place.
// ck = rwb·k uses ORIGINAL k (read before write); 8-lane shfl reduce.
// ckrb = (ck + rb_shifted) * ATT_SCALE * LOG2E (flash's per-j bias, log2 dom).
__global__ __launch_bounds__(256) void k_fold(
    f16* __restrict__ kh, const f16* __restrict__ Ke,
    const float* __restrict__ rwb, const float* __restrict__ rbias,
    float* __restrict__ ckrb)
{
    long gid = (long)blockIdx.x * 256 + threadIdx.x;   // 0 .. 524287
    int t8 = (int)(gid & 7);            // 8-f16 chunk within the 64-wide head seg
    long seg = gid >> 3;                // 0..65535 : seg = gm*16 + n
    int n = (int)(seg & 15);
    long gm = seg >> 4;                 // 0..4095
    int b = (int)(gm >> 10), j = (int)(gm & 1023);

    f16* kp = &kh[gm * 1024 + n * 64 + t8 * 8];
    f16x8 kv = *(f16x8*)kp;
    f16x8 ke = *(const f16x8*)&Ke[(((long)(b * 16 + n) << 10) + j) * 64 + t8 * 8];

    float dot = 0.0f;
    f16x8 ko;
#pragma unroll
    for (int e = 0; e < 8; ++e) {
        float kf = (float)kv[e];
        dot += kf * rwb[n * 64 + t8 * 8 + e];
        ko[e] = (f16)(kf + (float)ke[e]);
    }
    *(f16x8*)kp = ko;

    dot += __shfl_xor(dot, 1);
    dot += __shfl_xor(dot, 2);
    dot += __shfl_xor(dot, 4);
    if (t8 == 0) {
        float rbv = (j < 1023) ? rbias[(j + 1) * 16 + n] : 0.0f;
        ckrb[(((long)(b * 16 + n)) << 10) + j] = (dot + rbv) * (ATT_SCALE * LOG2E);
    }
}

// ---------------- NT GEMM: R8-exact body (BK=64, both-sides XOR swizzle, T1) ----------------
// Reverted from R13's fused epilogue (it cost +22us). Proven: ~41-42us QKV,
// conflicts == 0, FETCH ~28.8MB, bit-identical output.
template <int BM, int BN, int BK, int WROWS, int WCOLS, int EPI>
__global__ __launch_bounds__(256) void k_gemm_nt(
    const f16* __restrict__ A, const f16* __restrict__ Bt, void* __restrict__ Cv,
    f16* __restrict__ qtp, f16* __restrict__ ktp, f16* __restrict__ vtp,
    int lda, int ldb, int ldc, int K)
{
    static_assert(BK == 64, "geometry below assumes BK=64");
    constexpr int TM = BM / (WROWS * 16);
    constexpr int TN = BN / (WCOLS * 16);
    __shared__ __align__(16) f16 sA[BM * 64];
    __shared__ __align__(16) f16 sB[BN * 64];

    const int tid = threadIdx.x;
    const int lane = tid & 63, wave = tid >> 6;
    const int wm = wave / WCOLS, wn = wave % WCOLS;

    const int nwg = gridDim.x * gridDim.y;
    const int flat = blockIdx.y * gridDim.x + blockIdx.x;
    const int cpx = nwg >> 3;
    const int swz = (flat & 7) * cpx + (flat >> 3);
    const int bx = swz % gridDim.x, by = swz / gridDim.x;
    const int m0 = by * BM, n0 = bx * BN;

    f32x4 acc[TM][TN] = {};

    const int lrow = lane & 15;
    const int quad = lane >> 4;
    const int srow = lane >> 3;            // row within 1KB chunk (0..7)
    const int scol = ((lane & 7) ^ (srow & 7)) * 8;   // inverse-swizzled src chunk

    for (int k0 = 0; k0 < K; k0 += 64) {
        __syncthreads();
        constexpr int CHA = BM / 8;   // 1KB chunks per A tile
#pragma unroll
        for (int ch = 0; ch < CHA / 4; ++ch) {
            int cc = ch * 4 + wave;
            __builtin_amdgcn_global_load_lds(
                (const AS1 void*)(const void*)&A[(long)(m0 + cc * 8 + srow) * lda + k0 + scol],
                (AS3 void*)(void*)&sA[cc * 512], 16, 0, 0);
        }
        constexpr int CHB = BN / 8;
#pragma unroll
        for (int ch = 0; ch < CHB / 4; ++ch) {
            int cc = ch * 4 + wave;
            __builtin_amdgcn_global_load_lds(
                (const AS1 void*)(const void*)&Bt[(long)(n0 + cc * 8 + srow) * ldb + k0 + scol],
                (AS3 void*)(void*)&sB[cc * 512], 16, 0, 0);
        }
        __syncthreads();

        // two K=32 slices per staged 64-col tile; swizzled chunk = kc ^ (row&7)
#pragma unroll
        for (int kk = 0; kk < 2; ++kk) {
            const int kcb = kk * 4 + quad;   // global 16B-chunk index (0..7)
            f16x8 af[TM], bfr[TN];
#pragma unroll
            for (int mi = 0; mi < TM; ++mi) {
                int R = wm * TM * 16 + mi * 16 + lrow;
                af[mi] = *(const f16x8*)&sA[R * 64 + ((kcb ^ (lrow & 7)) * 8)];
            }
#pragma unroll
            for (int ni = 0; ni < TN; ++ni) {
                int R = wn * TN * 16 + ni * 16 + lrow;
                bfr[ni] = *(const f16x8*)&sB[R * 64 + ((kcb ^ (lrow & 7)) * 8)];
            }
#pragma unroll
            for (int mi = 0; mi < TM; ++mi)
#pragma unroll
                for (int ni = 0; ni < TN; ++ni)
                    acc[mi][ni] = __builtin_amdgcn_mfma_f32_16x16x32_f16(af[mi], bfr[ni], acc[mi][ni], 0, 0, 0);
        }
    }

    const int crow = (lane >> 4) * 4;
    const int ccol = lane & 15;
#pragma unroll
    for (int mi = 0; mi < TM; ++mi)
#pragma unroll
        for (int ni = 0; ni < TN; ++ni)
#pragma unroll
            for (int r = 0; r < 4; ++r) {
                int gm = m0 + wm * TM * 16 + mi * 16 + crow + r;
                int gn = n0 + wn * TN * 16 + ni * 16 + ccol;
                float val = acc[mi][ni][r];
                if constexpr (EPI == 0) {
                    ((f16*)Cv)[(long)gm * ldc + gn] = (f16)val;
                } else {
                    int seg = n0 >> 10;       // block-uniform (BN=128 | 1024)
                    int col = gn & 1023;
                    if (seg == 0) {
                        qtp[(long)gm * 1024 + col] = (f16)val;
                    } else if (seg == 1) {
                        ktp[(long)gm * 1024 + col] = (f16)val;
                    } else {
                        int b = gm >> 10, i = gm & 1023;
                        vtp[(((long)(b << 10) + col) << 10) + i] = (f16)val;
                    }
                }
            }
}

// ---------------- fused flash attention v16: K-folded (K'=k+ke, ck in bias).
// Byte-identical to R13's flash (measured ~37us inferred): S = q·K' + CKRB,
// S^T K-dim 64 (8 MFMA/iter), 2 staging streams, LDS 33KB, defer-max softmax,
// epilogue-deferred l reduction, no setprio (R11 A/B).
// Tripwires: WRITE == 8192 KB, FETCH ~12-13MB, VGPR <= 64, absmax <= 0.108.
__global__ __launch_bounds__(512, 4) void k_flash(
    const f16* __restrict__ qh, const f16* __restrict__ kh,
    const f16* __restrict__ vT, const float* __restrict__ ckrb,
    f16* __restrict__ avp)
{
    __shared__ __align__(16) f16 sKa[2][64 * 64];   // K' tile: [j-local][d]
    __shared__ __align__(16) f16 sVa[2][64 * 64];   // vT tile: [d][j-local]
    __shared__ float sRB[2][64];

    const int tid = threadIdx.x, lane = tid & 63, wave = tid >> 6;  // wave 0..7
    const int bid = blockIdx.x;
    const int h = (((bid >> 3) & 7) << 3) | (bid & 7);
    const int i0 = (bid >> 6) * 128;
    const int b = h >> 4, n = h & 15;

    const int lrow = lane & 15;            // q (B-frag n) / row index
    const int quad = lane >> 4;
    const int lr3 = lane >> 3;             // staging: row within wave's 8-row slice
    const int swc = (lane & 7) ^ (lr3 & 7);  // inverse-swizzled source 16B chunk

    // wave-slice per-lane source pointers (tile row = 8*wave + lr3)
    const f16* srcK = kh + ((long)(b * Qc) + 8 * wave + lr3) * 1024 + n * 64 + swc * 8;
    const f16* srcV = vT + (long)h * DHc * Qc + (long)(8 * wave + lr3) * Qc + swc * 8;

    // Q fragments (B-operand of S^T): wave owns q rows [i0+wave*16, +16).
    const f16 qsc = (f16)0.125f;
    f16x8 aq[2];
    {
        long rix = (long)(b * Qc + i0 + wave * 16 + lrow) * 1024 + n * 64;
        aq[0] = *(const f16x8*)&qh[rix + quad * 8] * qsc;        // k-dim [0,32)
        aq[1] = *(const f16x8*)&qh[rix + 32 + quad * 8] * qsc;   // k-dim [32,64)
    }

    float m_i = -1e30f, l_i = 0.0f;   // m: log2 domain, q-group uniform; l: per-lane partial
    f32x4 o_acc[4] = {};   // D[m=q][n=d]: row q=quad*4+reg, col d=lane&15

    // prologue: stage tile 0 (async) + rb0
    {
        float rbv = 0.0f;
        if (tid < 64) rbv = ckrb[((long)h << 10) + tid];
        __builtin_amdgcn_global_load_lds((const AS1 void*)srcK, (AS3 void*)&sKa[0][wave * 512], 16, 0, 0);
        __builtin_amdgcn_global_load_lds((const AS1 void*)srcV, (AS3 void*)&sVa[0][wave * 512], 16, 0, 0);
        if (tid < 64) sRB[0][tid] = rbv;
    }
    __syncthreads();   // drains vmcnt(0): tile 0 resident

    for (int jt = 0; jt < 16; ++jt) {
        const int cur = jt & 1;

        // issue next tile's async loads FIRST (in flight across compute below)
        float rbn = 0.0f;
        if (jt < 15) {
            const int j0n = (jt + 1) * 64;
            __builtin_amdgcn_global_load_lds((const AS1 void*)(srcK + (long)j0n * 1024),
                                             (AS3 void*)&sKa[cur ^ 1][wave * 512], 16, 0, 0);
            __builtin_amdgcn_global_load_lds((const AS1 void*)(srcV + j0n),
                                             (AS3 void*)&sVa[cur ^ 1][wave * 512], 16, 0, 0);
            if (tid < 64) rbn = ckrb[((long)h << 10) + j0n + tid];
        }

        const f16* Ka = &sKa[cur][0];
        const f16* Va = &sVa[cur][0];
        const int rsw = lrow & 7;

        // S^T: D[m=j][n=q], 64 j x 16 q per wave; K=64 (K' = k+ke)
        f32x4 s_acc[4] = {};
#pragma unroll
        for (int ni = 0; ni < 4; ++ni) {
            int rb_ = (ni * 16 + lrow) * 64;
            f16x8 a0 = *(const f16x8*)&Ka[rb_ + ((0 + quad) ^ rsw) * 8];
            f16x8 a1 = *(const f16x8*)&Ka[rb_ + ((4 + quad) ^ rsw) * 8];
            s_acc[ni] = __builtin_amdgcn_mfma_f32_16x16x32_f16(a0, aq[0], s_acc[ni], 0, 0, 0);
            s_acc[ni] = __builtin_amdgcn_mfma_f32_16x16x32_f16(a1, aq[1], s_acc[ni], 0, 0, 0);
        }

        // speculative online softmax (log2 domain): P = exp2(v - m_old) fused
        // with the max scan; rescale path only when the wave-uniform test fires.
        f16x4 pf[4];
        float mx = -1e30f, sm = 0.0f;
#pragma unroll
        for (int ni = 0; ni < 4; ++ni) {
            f32x4 rb4 = *(const f32x4*)&sRB[cur][ni * 16 + quad * 4];
            f16x4 pvv;
#pragma unroll
            for (int r = 0; r < 4; ++r) {
                float v = fmaf(s_acc[ni][r], LOG2E, rb4[r]);
                s_acc[ni][r] = v;
                mx = fmaxf(mx, v);
                float e = __builtin_amdgcn_exp2f(v - m_i);
                sm += e;
                pvv[r] = (f16)e;
            }
            pf[ni] = pvv;
        }
        if (!__all(mx - m_i <= 8.0f)) {
            float wmx = fmaxf(mx, __shfl_xor(mx, 16));
            wmx = fmaxf(wmx, __shfl_xor(wmx, 32));
            float mn = fmaxf(m_i, wmx);            // q-group uniform
            float alpha = __builtin_amdgcn_exp2f(m_i - mn);   // q-group uniform
            sm = 0.0f;
#pragma unroll
            for (int ni = 0; ni < 4; ++ni) {
                f16x4 pvv;
#pragma unroll
                for (int r = 0; r < 4; ++r) {
                    float e = __builtin_amdgcn_exp2f(s_acc[ni][r] - mn);
                    sm += e;
                    pvv[r] = (f16)e;
                }
                pf[ni] = pvv;
            }
            l_i *= alpha;   // uniform scaling keeps per-lane partials consistent
#pragma unroll
            for (int r = 0; r < 4; ++r) {
                float al = __shfl(alpha, quad * 4 + r);
#pragma unroll
                for (int dt = 0; dt < 4; ++dt) o_acc[dt][r] *= al;
            }
            m_i = mn;
        }
        l_i += sm;

        // PV: D[m=q][n=d] += P[q][j] * V[j][d], K=16 chunks, P from registers.
        // sVa read with source-matched swizzle (16B chunk ^ (d&7)).
#pragma unroll
        for (int nj = 0; nj < 4; ++nj) {
            int coff = ((2 * nj + (quad >> 1)) ^ rsw) * 8 + (quad & 1) * 4;
#pragma unroll
            for (int dt = 0; dt < 4; ++dt) {
                f16x4 bv = *(const f16x4*)&Va[(dt * 16 + lrow) * 64 + coff];
                o_acc[dt] = __builtin_amdgcn_mfma_f32_16x16x16f16(pf[nj], bv, o_acc[dt], 0, 0, 0);
            }
        }

        if (jt < 15) {
            if (tid < 64) sRB[cur ^ 1][tid] = rbn;
            __syncthreads();   // drains vmcnt: next tile resident; rb visible
        }
    }

    // epilogue: deferred cross-lane l reduction (valid: all partials share the
    // same q-group-uniform m scaling), then avp = O / l.
    l_i += __shfl_xor(l_i, 16);
    l_i += __shfl_xor(l_i, 32);
    {
        float linv = 1.0f / l_i;
#pragma unroll
        for (int r = 0; r < 4; ++r) {
            float li = __shfl(linv, quad * 4 + r);
            int i = i0 + wave * 16 + quad * 4 + r;
#pragma unroll
            for (int dt = 0; dt < 4; ++dt) {
                int d = dt * 16 + lrow;
                avp[((long)(b * Qc + i) << 10) + n * 64 + d] = (f16)(o_acc[dt][r] * li);
            }
        }
    }
}

// ---------------- residual + LayerNorm (w f32, ao f16; f32 output) ----------------
__global__ __launch_bounds__(256) void k_res_ln(const float* __restrict__ w, const f16* __restrict__ ao,
                                                const float* __restrict__ gamma, const float* __restrict__ beta,
                                                float* __restrict__ out) {
    const long base = (long)blockIdx.x * 1024;
    const int tid = threadIdx.x;
    float4 wv = *(const float4*)&w[base + tid * 4];
    f16x4 av = *(const f16x4*)&ao[base + tid * 4];
    float x[4] = { wv.x + (float)av[0], wv.y + (float)av[1],
                   wv.z + (float)av[2], wv.w + (float)av[3] };
    float s = x[0] + x[1] + x[2] + x[3];
    float s2 = x[0] * x[0] + x[1] * x[1] + x[2] * x[2] + x[3] * x[3];
#pragma unroll
    for (int off = 32; off; off >>= 1) { s += __shfl_down(s, off); s2 += __shfl_down(s2, off); }
    __shared__ float rs[4], rs2[4];
    if ((tid & 63) == 0) { rs[tid >> 6] = s; rs2[tid >> 6] = s2; }
    __syncthreads();
    s = rs[0] + rs[1] + rs[2] + rs[3];
    s2 = rs2[0] + rs2[1] + rs2[2] + rs2[3];
    float mu = s * (1.0f / 1024.0f);
    float var = s2 * (1.0f / 1024.0f) - mu * mu;
    float inv = rsqrtf(var + 1e-5f);
    float4 gv = *(const float4*)&gamma[tid * 4];
    float4 bv = *(const float4*)&beta[tid * 4];
    float4 o;
    o.x = (x[0] - mu) * inv * gv.x + bv.x;
    o.y = (x[1] - mu) * inv * gv.y + bv.y;
    o.z = (x[2] - mu) * inv * gv.z + bv.z;
    o.w = (x[3] - mu) * inv * gv.w + bv.w;
    *(float4*)&out[base + tid * 4] = o;
}

extern "C" void kernel_launch(void* const* d_in, const int* in_sizes, int n_in,
                              void* d_out, int out_size, void* d_ws, size_t ws_size,
                              hipStream_t stream) {
    const float* w_in   = (const float*)d_in[0];
    const float* r_emb  = (const float*)d_in[1];
    const float* r_wb   = (const float*)d_in[2];
    const float* r_bias = (const float*)d_in[3];
    const float* Wq     = (const float*)d_in[4];
    const float* Wk     = (const float*)d_in[5];
    const float* Wv     = (const float*)d_in[6];
    const float* Wo     = (const float*)d_in[7];
    const float* ln_g   = (const float*)d_in[8];
    const float* ln_b   = (const float*)d_in[9];
    float* out = (float*)d_out;

    // workspace carve-out (48.25MB fixed + aliases)
    char* p = (char*)d_ws;
    auto alloc = [&](size_t bytes) { char* r = p; p += (bytes + 255) & ~(size_t)255; return r; };
    f16* wh = (f16*)alloc((size_t)BQ * Dc * 2);          // 8 MB
    f16* WT = (f16*)alloc((size_t)4 * Dc * Dc * 2);      // 8 MB: WqT,WkT,WvT,WoT (contiguous)
    f16* qh = (f16*)alloc((size_t)BQ * Dc * 2);          // 8 MB [b*Q+i][n*64+d]
    f16* kh = (f16*)alloc((size_t)BQ * Dc * 2);          // 8 MB [b*Q+j][n*64+d] -> K' after fold
    f16* Ke = (f16*)alloc((size_t)NHEAD * Qc * DHc * 2); // 8 MB [h][j][64] rel-shifted r_emb
    f16* vT = (f16*)alloc((size_t)BQ * Dc * 2);          // 8 MB [b][dcol][j]
    float* ckrb = (float*)alloc((size_t)NHEAD * Qc * 4); // 256 KB (rwb·k + rb)*scale*log2e
    f16* WoT = WT + (size_t)3 * Dc * Dc;
    // aliases (liveness-checked): wh dead after QKV GEMM; Ke dead after k_fold
    f16* avp = wh;                 // [b][i][1024] f16
    f16* ao  = Ke;                 // 8 MB f16

    // 1. merged preprocessing: f2h + weight transpose + Ke fill (one dispatch)
    Ptr4 srcs{{Wq, Wk, Wv, Wo}};
    k_prep<<<8192, 256, 0, stream>>>(w_in, wh, srcs, WT, r_emb, Ke);

    // 2. fused QKV projection (R8-exact): dim3(24,32), BM=128/BK=64
    k_gemm_nt<128, 128, 64, 2, 2, 5><<<dim3(3 * Dc / 128, BQ / 128), 256, 0, stream>>>(
        wh, WT, nullptr, qh, kh, vT, Dc, Dc, 0, Dc);

    // 3. K-fold: kh += Ke (in place) + ckrb = (rwb·k + rb)*scale*log2e
    k_fold<<<2048, 256, 0, stream>>>(kh, Ke, r_wb, r_bias, ckrb);

    // 4. fused attention (XCD-swizzled 1D grid 512, 8-wave blocks, async dbuf, K=64)
    k_flash<<<512, 512, 0, stream>>>(qh, kh, vT, ckrb, avp);

    // 5. attn_out = avp @ Wo^T (64x128 tile -> 512 blocks; f16 out into aliased ao)
    k_gemm_nt<64, 128, 64, 2, 2, 0><<<dim3(Dc / 128, BQ / 64), 256, 0, stream>>>(
        avp, WoT, ao, nullptr, nullptr, nullptr, Dc, Dc, Dc, Dc);

    // 6. out = LayerNorm(w + attn_out), fp32 output
    k_res_ln<<<BQ, 256, 0, stream>>>(w_in, ao, ln_g, ln_b, out);
}

// Round 15
// 197.910 us; speedup vs baseline: 1.0738x; 1.0486x over previous
//
#include <hip/hip_runtime.h>
#include <hip/hip_bf16.h>

using f16 = _Float16;
typedef _Float16 f16x8 __attribute__((ext_vector_type(8)));
typedef _Float16 f16x4 __attribute__((ext_vector_type(4)));
typedef float f32x4 __attribute__((ext_vector_type(4)));

#define AS1 __attribute__((address_space(1)))
#define AS3 __attribute__((address_space(3)))

// Problem constants
constexpr int Bc = 4, Qc = 1024, Dc = 1024, Nh = 16, DHc = 64;
constexpr int BQ = Bc * Qc;      // 4096 rows of w
constexpr int NHEAD = Bc * Nh;   // 64 (b,n) heads
constexpr float ATT_SCALE = 0.125f;
constexpr float LOG2E = 1.44269504088896f;

// ---------------- merged preprocessing: f2h | 4-way transpose | rel-shift r_emb ----------------
struct Ptr4 { const float* p[4]; };
__global__ __launch_bounds__(256) void k_prep(
    const float* __restrict__ w_in, f16* __restrict__ wh,
    Ptr4 srcs, f16* __restrict__ WT,
    const float* __restrict__ remb, f16* __restrict__ Ke)
{
    const int bid = blockIdx.x, tid = threadIdx.x;
    if (bid < 2048) {
        long i8 = ((long)bid * 256 + tid) * 8;
        float4 a = *(const float4*)&w_in[i8];
        float4 b = *(const float4*)&w_in[i8 + 4];
        f16x8 o = { (f16)a.x, (f16)a.y, (f16)a.z, (f16)a.w,
                    (f16)b.x, (f16)b.y, (f16)b.z, (f16)b.w };
        *(f16x8*)&wh[i8] = o;
    } else if (bid < 6144) {
        __shared__ f16 tile[32][33];
        int idx = bid - 2048;
        int z = idx >> 10, rem = idx & 1023;
        int r0 = (rem >> 5) * 32, c0 = (rem & 31) * 32;
        const float* src = srcs.p[z];
        f16* d = WT + (long)z * Dc * Dc;
        int tx = tid & 31, ty = tid >> 5;   // 32 x 8
#pragma unroll
        for (int dy = 0; dy < 32; dy += 8) {
            int r = r0 + ty + dy, c = c0 + tx;
            tile[ty + dy][tx] = (f16)src[(long)r * Dc + c];
        }
        __syncthreads();
#pragma unroll
        for (int dy = 0; dy < 32; dy += 8) {
            int c = c0 + ty + dy, r = r0 + tx;
            d[(long)c * Dc + r] = tile[tx][ty + dy];
        }
    } else {
        long gid = (long)(bid - 6144) * 256 + tid;  // 64*1024*8
        int d8 = (int)(gid & 7) * 8;
        int j = (int)((gid >> 3) & 1023);
        int h = (int)(gid >> 13);
        int n = h & 15;
        f16x8 kv;
        if (j < 1023) {
            const float* rp = &remb[((long)(j + 1) * 16 + n) * 64 + d8];
            float4 r0 = *(const float4*)rp, r1 = *(const float4*)(rp + 4);
            kv[0] = (f16)r0.x; kv[1] = (f16)r0.y; kv[2] = (f16)r0.z; kv[3] = (f16)r0.w;
            kv[4] = (f16)r1.x; kv[5] = (f16)r1.y; kv[6] = (f16)r1.z; kv[7] = (f16)r1.w;
        } else {
            kv = f16x8{};
        }
        *(f16x8*)&Ke[(((long)h << 10) + j) * 64 + d8] = kv;
    }
}

// ---------------- K-fold streaming kernel: kh += Ke (in place) + ckrb dot ----------------
__global__ __launch_bounds__(256) void k_fold(
    f16* __restrict__ kh, const f16* __restrict__ Ke,
    const float* __restrict__ rwb, const float* __restrict__ rbias,
    float* __restrict__ ckrb)
{
    long gid = (long)blockIdx.x * 256 + threadIdx.x;   // 0 .. 524287
    int t8 = (int)(gid & 7);            // 8-f16 chunk within the 64-wide head seg
    long seg = gid >> 3;                // 0..65535 : seg = gm*16 + n
    int n = (int)(seg & 15);
    long gm = seg >> 4;                 // 0..4095
    int b = (int)(gm >> 10), j = (int)(gm & 1023);

    f16* kp = &kh[gm * 1024 + n * 64 + t8 * 8];
    f16x8 kv = *(f16x8*)kp;
    f16x8 ke = *(const f16x8*)&Ke[(((long)(b * 16 + n) << 10) + j) * 64 + t8 * 8];

    float dot = 0.0f;
    f16x8 ko;
#pragma unroll
    for (int e = 0; e < 8; ++e) {
        float kf = (float)kv[e];
        dot += kf * rwb[n * 64 + t8 * 8 + e];
        ko[e] = (f16)(kf + (float)ke[e]);
    }
    *(f16x8*)kp = ko;

    dot += __shfl_xor(dot, 1);
    dot += __shfl_xor(dot, 2);
    dot += __shfl_xor(dot, 4);
    if (t8 == 0) {
        float rbv = (j < 1023) ? rbias[(j + 1) * 16 + n] : 0.0f;
        ckrb[(((long)(b * 16 + n)) << 10) + j] = (dot + rbv) * (ATT_SCALE * LOG2E);
    }
}

// ---------------- NT GEMM: R8-exact body (BK=64, both-sides XOR swizzle, T1) ----------------
template <int BM, int BN, int BK, int WROWS, int WCOLS, int EPI>
__global__ __launch_bounds__(256) void k_gemm_nt(
    const f16* __restrict__ A, const f16* __restrict__ Bt, void* __restrict__ Cv,
    f16* __restrict__ qtp, f16* __restrict__ ktp, f16* __restrict__ vtp,
    int lda, int ldb, int ldc, int K)
{
    static_assert(BK == 64, "geometry below assumes BK=64");
    constexpr int TM = BM / (WROWS * 16);
    constexpr int TN = BN / (WCOLS * 16);
    __shared__ __align__(16) f16 sA[BM * 64];
    __shared__ __align__(16) f16 sB[BN * 64];

    const int tid = threadIdx.x;
    const int lane = tid & 63, wave = tid >> 6;
    const int wm = wave / WCOLS, wn = wave % WCOLS;

    const int nwg = gridDim.x * gridDim.y;
    const int flat = blockIdx.y * gridDim.x + blockIdx.x;
    const int cpx = nwg >> 3;
    const int swz = (flat & 7) * cpx + (flat >> 3);
    const int bx = swz % gridDim.x, by = swz / gridDim.x;
    const int m0 = by * BM, n0 = bx * BN;

    f32x4 acc[TM][TN] = {};

    const int lrow = lane & 15;
    const int quad = lane >> 4;
    const int srow = lane >> 3;            // row within 1KB chunk (0..7)
    const int scol = ((lane & 7) ^ (srow & 7)) * 8;   // inverse-swizzled src chunk

    for (int k0 = 0; k0 < K; k0 += 64) {
        __syncthreads();
        constexpr int CHA = BM / 8;   // 1KB chunks per A tile
#pragma unroll
        for (int ch = 0; ch < CHA / 4; ++ch) {
            int cc = ch * 4 + wave;
            __builtin_amdgcn_global_load_lds(
                (const AS1 void*)(const void*)&A[(long)(m0 + cc * 8 + srow) * lda + k0 + scol],
                (AS3 void*)(void*)&sA[cc * 512], 16, 0, 0);
        }
        constexpr int CHB = BN / 8;
#pragma unroll
        for (int ch = 0; ch < CHB / 4; ++ch) {
            int cc = ch * 4 + wave;
            __builtin_amdgcn_global_load_lds(
                (const AS1 void*)(const void*)&Bt[(long)(n0 + cc * 8 + srow) * ldb + k0 + scol],
                (AS3 void*)(void*)&sB[cc * 512], 16, 0, 0);
        }
        __syncthreads();

        // two K=32 slices per staged 64-col tile; swizzled chunk = kc ^ (row&7)
#pragma unroll
        for (int kk = 0; kk < 2; ++kk) {
            const int kcb = kk * 4 + quad;   // global 16B-chunk index (0..7)
            f16x8 af[TM], bfr[TN];
#pragma unroll
            for (int mi = 0; mi < TM; ++mi) {
                int R = wm * TM * 16 + mi * 16 + lrow;
                af[mi] = *(const f16x8*)&sA[R * 64 + ((kcb ^ (lrow & 7)) * 8)];
            }
#pragma unroll
            for (int ni = 0; ni < TN; ++ni) {
                int R = wn * TN * 16 + ni * 16 + lrow;
                bfr[ni] = *(const f16x8*)&sB[R * 64 + ((kcb ^ (lrow & 7)) * 8)];
            }
#pragma unroll
            for (int mi = 0; mi < TM; ++mi)
#pragma unroll
                for (int ni = 0; ni < TN; ++ni)
                    acc[mi][ni] = __builtin_amdgcn_mfma_f32_16x16x32_f16(af[mi], bfr[ni], acc[mi][ni], 0, 0, 0);
        }
    }

    const int crow = (lane >> 4) * 4;
    const int ccol = lane & 15;
#pragma unroll
    for (int mi = 0; mi < TM; ++mi)
#pragma unroll
        for (int ni = 0; ni < TN; ++ni)
#pragma unroll
            for (int r = 0; r < 4; ++r) {
                int gm = m0 + wm * TM * 16 + mi * 16 + crow + r;
                int gn = n0 + wn * TN * 16 + ni * 16 + ccol;
                float val = acc[mi][ni][r];
                if constexpr (EPI == 0) {
                    ((f16*)Cv)[(long)gm * ldc + gn] = (f16)val;
                } else {
                    int seg = n0 >> 10;       // block-uniform (BN=128 | 1024)
                    int col = gn & 1023;
                    if (seg == 0) {
                        qtp[(long)gm * 1024 + col] = (f16)val;
                    } else if (seg == 1) {
                        ktp[(long)gm * 1024 + col] = (f16)val;
                    } else {
                        int b = gm >> 10, i = gm & 1023;
                        vtp[(((long)(b << 10) + col) << 10) + i] = (f16)val;
                    }
                }
            }
}

// ---------------- fused flash attention v17: v16 + KVBLK=128 (half the barriers).
// Post-K-fold LDS headroom makes the 128-j tile affordable double-buffered:
// 2x[128x64] K' + 2x[64x128] V + RB = 65 KB <= 80 KB at 2 blocks/CU. Same
// MFMA/softmax/staging totals, but 8 iters instead of 16 -> half the
// __syncthreads (each barrier amplifies softmax-path jitter across 8 waves)
// and 2x longer prefetch hide window. V-row swizzle re-derived for 16-chunk
// rows: c' = (c&8) | ((c&7) ^ (d&7)) on BOTH sides (rule #21); K' rows
// unchanged (128B, XOR rsw). Softmax/defer-max/deferred-l unchanged.
// Tripwires: WRITE == 8192 KB, FETCH ~12-13MB, LDS ~66.5KB, VGPR <= 96,
// absmax == 0.03125. If flash gain < 2us -> barrier theory dead, plateau.
__global__ __launch_bounds__(512, 4) void k_flash(
    const f16* __restrict__ qh, const f16* __restrict__ kh,
    const f16* __restrict__ vT, const float* __restrict__ ckrb,
    f16* __restrict__ avp)
{
    __shared__ __align__(16) f16 sKa[2][128 * 64];   // K' tile: [j-local][d]
    __shared__ __align__(16) f16 sVa[2][64 * 128];   // vT tile: [d][j-local]
    __shared__ float sRB[2][128];

    const int tid = threadIdx.x, lane = tid & 63, wave = tid >> 6;  // wave 0..7
    const int bid = blockIdx.x;
    const int h = (((bid >> 3) & 7) << 3) | (bid & 7);
    const int i0 = (bid >> 6) * 128;
    const int b = h >> 4, n = h & 15;

    const int lrow = lane & 15;            // q (B-frag n) / row index
    const int quad = lane >> 4;

    // K' staging: wave covers 16 j-rows (two 8-row ops); row 128B = 8 chunks
    const int lr3 = lane >> 3;                         // row within 8-row op
    const int swcK = (lane & 7) ^ (lr3 & 7);           // inv-swizzled 16B chunk
    const f16* srcK = kh + ((long)(b * Qc) + 16 * wave + lr3) * 1024 + n * 64 + swcK * 8;

    // V staging: wave covers 8 d-rows (two 4-row ops); row 256B = 16 chunks
    const int lv4 = lane >> 4;                         // row within 4-row op (0..3)
    const int c16 = lane & 15;
    const int d0 = 8 * wave + lv4;                     // op0 d-row
    const int swcV0 = (c16 & 8) | ((c16 & 7) ^ (d0 & 7));
    const int swcV1 = (c16 & 8) | ((c16 & 7) ^ ((d0 + 4) & 7));
    const f16* srcVb = vT + (long)h * DHc * Qc;

    // Q fragments (B-operand of S^T): wave owns q rows [i0+wave*16, +16).
    const f16 qsc = (f16)0.125f;
    f16x8 aq[2];
    {
        long rix = (long)(b * Qc + i0 + wave * 16 + lrow) * 1024 + n * 64;
        aq[0] = *(const f16x8*)&qh[rix + quad * 8] * qsc;        // k-dim [0,32)
        aq[1] = *(const f16x8*)&qh[rix + 32 + quad * 8] * qsc;   // k-dim [32,64)
    }

    auto stage = [&](int buf, int j0) {
        __builtin_amdgcn_global_load_lds((const AS1 void*)(srcK + (long)j0 * 1024),
                                         (AS3 void*)&sKa[buf][wave * 1024], 16, 0, 0);
        __builtin_amdgcn_global_load_lds((const AS1 void*)(srcK + (long)(j0 + 8) * 1024),
                                         (AS3 void*)&sKa[buf][wave * 1024 + 512], 16, 0, 0);
        __builtin_amdgcn_global_load_lds((const AS1 void*)(srcVb + (long)d0 * Qc + j0 + swcV0 * 8),
                                         (AS3 void*)&sVa[buf][wave * 1024], 16, 0, 0);
        __builtin_amdgcn_global_load_lds((const AS1 void*)(srcVb + (long)(d0 + 4) * Qc + j0 + swcV1 * 8),
                                         (AS3 void*)&sVa[buf][wave * 1024 + 512], 16, 0, 0);
    };

    float m_i = -1e30f, l_i = 0.0f;   // m: log2 domain, q-group uniform; l: per-lane partial
    f32x4 o_acc[4] = {};   // D[m=q][n=d]: row q=quad*4+reg, col d=lane&15

    // prologue: stage tile 0 (async) + rb0
    {
        float rbv = 0.0f;
        if (tid < 128) rbv = ckrb[((long)h << 10) + tid];
        stage(0, 0);
        if (tid < 128) sRB[0][tid] = rbv;
    }
    __syncthreads();   // drains vmcnt(0): tile 0 resident

    for (int jt = 0; jt < 8; ++jt) {
        const int cur = jt & 1;

        // issue next tile's async loads FIRST (in flight across compute below)
        float rbn = 0.0f;
        if (jt < 7) {
            const int j0n = (jt + 1) * 128;
            stage(cur ^ 1, j0n);
            if (tid < 128) rbn = ckrb[((long)h << 10) + j0n + tid];
        }

        const f16* Ka = &sKa[cur][0];
        const f16* Va = &sVa[cur][0];
        const int rsw = lrow & 7;

        // S^T: D[m=j][n=q], 128 j x 16 q per wave; K=64 (K' = k+ke)
        f32x4 s_acc[8] = {};
#pragma unroll
        for (int ni = 0; ni < 8; ++ni) {
            int rb_ = (ni * 16 + lrow) * 64;
            f16x8 a0 = *(const f16x8*)&Ka[rb_ + ((0 + quad) ^ rsw) * 8];
            f16x8 a1 = *(const f16x8*)&Ka[rb_ + ((4 + quad) ^ rsw) * 8];
            s_acc[ni] = __builtin_amdgcn_mfma_f32_16x16x32_f16(a0, aq[0], s_acc[ni], 0, 0, 0);
            s_acc[ni] = __builtin_amdgcn_mfma_f32_16x16x32_f16(a1, aq[1], s_acc[ni], 0, 0, 0);
        }

        // speculative online softmax (log2 domain): P = exp2(v - m_old) fused
        // with the max scan; rescale path only when the wave-uniform test fires.
        f16x4 pf[8];
        float mx = -1e30f, sm = 0.0f;
#pragma unroll
        for (int ni = 0; ni < 8; ++ni) {
            f32x4 rb4 = *(const f32x4*)&sRB[cur][ni * 16 + quad * 4];
            f16x4 pvv;
#pragma unroll
            for (int r = 0; r < 4; ++r) {
                float v = fmaf(s_acc[ni][r], LOG2E, rb4[r]);
                s_acc[ni][r] = v;
                mx = fmaxf(mx, v);
                float e = __builtin_amdgcn_exp2f(v - m_i);
                sm += e;
                pvv[r] = (f16)e;
            }
            pf[ni] = pvv;
        }
        if (!__all(mx - m_i <= 8.0f)) {
            float wmx = fmaxf(mx, __shfl_xor(mx, 16));
            wmx = fmaxf(wmx, __shfl_xor(wmx, 32));
            float mn = fmaxf(m_i, wmx);            // q-group uniform
            float alpha = __builtin_amdgcn_exp2f(m_i - mn);   // q-group uniform
            sm = 0.0f;
#pragma unroll
            for (int ni = 0; ni < 8; ++ni) {
                f16x4 pvv;
#pragma unroll
                for (int r = 0; r < 4; ++r) {
                    float e = __builtin_amdgcn_exp2f(s_acc[ni][r] - mn);
                    sm += e;
                    pvv[r] = (f16)e;
                }
                pf[ni] = pvv;
            }
            l_i *= alpha;   // uniform scaling keeps per-lane partials consistent
#pragma unroll
            for (int r = 0; r < 4; ++r) {
                float al = __shfl(alpha, quad * 4 + r);
#pragma unroll
                for (int dt = 0; dt < 4; ++dt) o_acc[dt][r] *= al;
            }
            m_i = mn;
        }
        l_i += sm;

        // PV: D[m=q][n=d] += P[q][j] * V[j][d], K=16 chunks, P from registers.
        // sVa rows are 128 f16 = 16 chunks; swizzle c' = (c&8)|((c&7)^rsw).
#pragma unroll
        for (int nj = 0; nj < 8; ++nj) {
            int c = 2 * nj + (quad >> 1);
            int coff = ((c & 8) | ((c & 7) ^ rsw)) * 8 + (quad & 1) * 4;
#pragma unroll
            for (int dt = 0; dt < 4; ++dt) {
                f16x4 bv = *(const f16x4*)&Va[(dt * 16 + lrow) * 128 + coff];
                o_acc[dt] = __builtin_amdgcn_mfma_f32_16x16x16f16(pf[nj], bv, o_acc[dt], 0, 0, 0);
            }
        }

        if (jt < 7) {
            if (tid < 128) sRB[cur ^ 1][tid] = rbn;
            __syncthreads();   // drains vmcnt: next tile resident; rb visible
        }
    }

    // epilogue: deferred cross-lane l reduction (valid: all partials share the
    // same q-group-uniform m scaling), then avp = O / l.
    l_i += __shfl_xor(l_i, 16);
    l_i += __shfl_xor(l_i, 32);
    {
        float linv = 1.0f / l_i;
#pragma unroll
        for (int r = 0; r < 4; ++r) {
            float li = __shfl(linv, quad * 4 + r);
            int i = i0 + wave * 16 + quad * 4 + r;
#pragma unroll
            for (int dt = 0; dt < 4; ++dt) {
                int d = dt * 16 + lrow;
                avp[((long)(b * Qc + i) << 10) + n * 64 + d] = (f16)(o_acc[dt][r] * li);
            }
        }
    }
}

// ---------------- residual + LayerNorm (w f32, ao f16; f32 output) ----------------
__global__ __launch_bounds__(256) void k_res_ln(const float* __restrict__ w, const f16* __restrict__ ao,
                                                const float* __restrict__ gamma, const float* __restrict__ beta,
                                                float* __restrict__ out) {
    const long base = (long)blockIdx.x * 1024;
    const int tid = threadIdx.x;
    float4 wv = *(const float4*)&w[base + tid * 4];
    f16x4 av = *(const f16x4*)&ao[base + tid * 4];
    float x[4] = { wv.x + (float)av[0], wv.y + (float)av[1],
                   wv.z + (float)av[2], wv.w + (float)av[3] };
    float s = x[0] + x[1] + x[2] + x[3];
    float s2 = x[0] * x[0] + x[1] * x[1] + x[2] * x[2] + x[3] * x[3];
#pragma unroll
    for (int off = 32; off; off >>= 1) { s += __shfl_down(s, off); s2 += __shfl_down(s2, off); }
    __shared__ float rs[4], rs2[4];
    if ((tid & 63) == 0) { rs[tid >> 6] = s; rs2[tid >> 6] = s2; }
    __syncthreads();
    s = rs[0] + rs[1] + rs[2] + rs[3];
    s2 = rs2[0] + rs2[1] + rs2[2] + rs2[3];
    float mu = s * (1.0f / 1024.0f);
    float var = s2 * (1.0f / 1024.0f) - mu * mu;
    float inv = rsqrtf(var + 1e-5f);
    float4 gv = *(const float4*)&gamma[tid * 4];
    float4 bv = *(const float4*)&beta[tid * 4];
    float4 o;
    o.x = (x[0] - mu) * inv * gv.x + bv.x;
    o.y = (x[1] - mu) * inv * gv.y + bv.y;
    o.z = (x[2] - mu) * inv * gv.z + bv.z;
    o.w = (x[3] - mu) * inv * gv.w + bv.w;
    *(float4*)&out[base + tid * 4] = o;
}

extern "C" void kernel_launch(void* const* d_in, const int* in_sizes, int n_in,
                              void* d_out, int out_size, void* d_ws, size_t ws_size,
                              hipStream_t stream) {
    const float* w_in   = (const float*)d_in[0];
    const float* r_emb  = (const float*)d_in[1];
    const float* r_wb   = (const float*)d_in[2];
    const float* r_bias = (const float*)d_in[3];
    const float* Wq     = (const float*)d_in[4];
    const float* Wk     = (const float*)d_in[5];
    const float* Wv     = (const float*)d_in[6];
    const float* Wo     = (const float*)d_in[7];
    const float* ln_g   = (const float*)d_in[8];
    const float* ln_b   = (const float*)d_in[9];
    float* out = (float*)d_out;

    // workspace carve-out (48.25MB fixed + aliases)
    char* p = (char*)d_ws;
    auto alloc = [&](size_t bytes) { char* r = p; p += (bytes + 255) & ~(size_t)255; return r; };
    f16* wh = (f16*)alloc((size_t)BQ * Dc * 2);          // 8 MB
    f16* WT = (f16*)alloc((size_t)4 * Dc * Dc * 2);      // 8 MB: WqT,WkT,WvT,WoT (contiguous)
    f16* qh = (f16*)alloc((size_t)BQ * Dc * 2);          // 8 MB [b*Q+i][n*64+d]
    f16* kh = (f16*)alloc((size_t)BQ * Dc * 2);          // 8 MB [b*Q+j][n*64+d] -> K' after fold
    f16* Ke = (f16*)alloc((size_t)NHEAD * Qc * DHc * 2); // 8 MB [h][j][64] rel-shifted r_emb
    f16* vT = (f16*)alloc((size_t)BQ * Dc * 2);          // 8 MB [b][dcol][j]
    float* ckrb = (float*)alloc((size_t)NHEAD * Qc * 4); // 256 KB (rwb·k + rb)*scale*log2e
    f16* WoT = WT + (size_t)3 * Dc * Dc;
    // aliases (liveness-checked): wh dead after QKV GEMM; Ke dead after k_fold
    f16* avp = wh;                 // [b][i][1024] f16
    f16* ao  = Ke;                 // 8 MB f16

    // 1. merged preprocessing: f2h + weight transpose + Ke fill (one dispatch)
    Ptr4 srcs{{Wq, Wk, Wv, Wo}};
    k_prep<<<8192, 256, 0, stream>>>(w_in, wh, srcs, WT, r_emb, Ke);

    // 2. fused QKV projection (R8-exact): dim3(24,32), BM=128/BK=64
    k_gemm_nt<128, 128, 64, 2, 2, 5><<<dim3(3 * Dc / 128, BQ / 128), 256, 0, stream>>>(
        wh, WT, nullptr, qh, kh, vT, Dc, Dc, 0, Dc);

    // 3. K-fold: kh += Ke (in place) + ckrb = (rwb·k + rb)*scale*log2e
    k_fold<<<2048, 256, 0, stream>>>(kh, Ke, r_wb, r_bias, ckrb);

    // 4. fused attention (XCD-swizzled 1D grid 512, KVBLK=128, async dbuf, K=64)
    k_flash<<<512, 512, 0, stream>>>(qh, kh, vT, ckrb, avp);

    // 5. attn_out = avp @ Wo^T (64x128 tile -> 512 blocks; f16 out into aliased ao)
    k_gemm_nt<64, 128, 64, 2, 2, 0><<<dim3(Dc / 128, BQ / 64), 256, 0, stream>>>(
        avp, WoT, ao, nullptr, nullptr, nullptr, Dc, Dc, Dc, Dc);

    // 6. out = LayerNorm(w + attn_out), fp32 output
    k_res_ln<<<BQ, 256, 0, stream>>>(w_in, ao, ln_g, ln_b, out);
}